// Round 13
// baseline (305.019 us; speedup 1.0000x reference)
//
#include <hip/hip_runtime.h>
#include <hip/hip_bf16.h>
#include <cmath>

// Problem constants
#define NN 768
#define CS 384
#define CZ 128
#define CH 16
#define HH 12
#define PQ 4
#define PV 8
#define CATC 2112           // H*(CZ+CH+PV*4)

typedef __attribute__((ext_vector_type(8))) __bf16 bf16x8;
typedef __attribute__((ext_vector_type(8))) unsigned short us8;
typedef __attribute__((ext_vector_type(4))) float f32x4;

__device__ __forceinline__ unsigned short f2bf(float f) {
  unsigned int u = __builtin_bit_cast(unsigned int, f);
  u += 0x7FFFu + ((u >> 16) & 1u);   // RNE
  return (unsigned short)(u >> 16);
}
__device__ __forceinline__ float bf2f(unsigned short u) {
  return __builtin_bit_cast(float, ((unsigned int)u) << 16);
}
__device__ __forceinline__ unsigned short nf2bf(float f) {
  __bf16 b = (__bf16)f;
  return __builtin_bit_cast(unsigned short, b);
}

// ---------------------------------------------------------------------------
// K_PROJG: projection GEMM, 8 i-rows/block, fp32, grid 96 x 384.
// Thread owns 3 virtual columns {t, t+384, t+768} of [Wq|Wkv|Wqp|Wkvp],
// read DIRECTLY from the four matrices (per-wave contiguous lanes -> coalesced).
__global__ void __launch_bounds__(384) k_projg(
    const float* __restrict__ s,
    const float* __restrict__ Wq, const float* __restrict__ Wkv,
    const float* __restrict__ Wqp, const float* __restrict__ Wkvp,
    const float* __restrict__ rot, const float* __restrict__ trans,
    const float* __restrict__ bq, const float* __restrict__ bkv,
    const float* __restrict__ bqp, const float* __restrict__ bkvp,
    float* __restrict__ q, float* __restrict__ kk, float* __restrict__ vv,
    float* __restrict__ qpts, float* __restrict__ kvpts) {
  __shared__ float sl[8][384];
  __shared__ float raw[8][576];    // [rawq(144)|rawkv(432)] per i, bias included
  __shared__ float Rl[8][9];
  __shared__ float Tl[8][3];
  int i0 = blockIdx.x*8, t = threadIdx.x;
  #pragma unroll
  for (int k = 0; k < 8; k++) sl[k][t] = s[(size_t)(i0+k)*CS + t];
  if (t < 72) Rl[t/9][t%9] = rot[(size_t)i0*9 + t];
  else if (t < 96) { int u = t-72; Tl[u/3][u%3] = trans[(size_t)i0*3 + u]; }
  __syncthreads();

  // column -> (matrix base, stride, col) mapping
  const float* w0; int s0_, c0_;
  const float* w1; int s1_, c1_;
  const float* w2; int s2_, c2_;
  if (t < 192) { w0 = Wq;   s0_ = 192; c0_ = t; }
  else         { w0 = Wkv;  s0_ = 384; c0_ = t - 192; }
  if (t < 192)      { w1 = Wkv;  s1_ = 384; c1_ = t + 192; }
  else if (t < 336) { w1 = Wqp;  s1_ = 144; c1_ = t - 192; }
  else              { w1 = Wkvp; s1_ = 432; c1_ = t - 336; }
  w2 = Wkvp; s2_ = 432; c2_ = t + 48;

  float a0[8], a1[8], a2[8];
  #pragma unroll
  for (int g = 0; g < 8; g++) { a0[g]=0.f; a1[g]=0.f; a2[g]=0.f; }
  #pragma unroll 4
  for (int c4 = 0; c4 < 96; c4++) {
    float4 sv[8];
    #pragma unroll
    for (int g = 0; g < 8; g++) sv[g] = *(const float4*)&sl[g][c4*4];
    #pragma unroll
    for (int e = 0; e < 4; e++) {
      int c = c4*4 + e;
      float wv0 = w0[(size_t)c*s0_ + c0_];
      float wv1 = w1[(size_t)c*s1_ + c1_];
      float wv2 = w2[(size_t)c*s2_ + c2_];
      #pragma unroll
      for (int g = 0; g < 8; g++) {
        float svv = (e==0)?sv[g].x:(e==1)?sv[g].y:(e==2)?sv[g].z:sv[g].w;
        a0[g] += svv*wv0; a1[g] += svv*wv1; a2[g] += svv*wv2;
      }
    }
  }
  // scatter col0 = t
  if (t < 192) {
    float b = bq[t];
    #pragma unroll
    for (int g = 0; g < 8; g++) q[(size_t)(i0+g)*192 + t] = a0[g] + b;
  } else {
    int cc = t - 192;
    float b = bkv[cc];
    int h = cc >> 5, u2 = cc & 31;
    #pragma unroll
    for (int g = 0; g < 8; g++) {
      float v = a0[g] + b;
      if (u2 < 16) kk[(size_t)(i0+g)*192 + h*16 + u2] = v;
      else         vv[(size_t)(i0+g)*192 + h*16 + (u2-16)] = v;
    }
  }
  // scatter col1 = t+384
  if (t < 192) {
    int cc = t + 192;
    float b = bkv[cc];
    int h = cc >> 5, u2 = cc & 31;
    #pragma unroll
    for (int g = 0; g < 8; g++) {
      float v = a1[g] + b;
      if (u2 < 16) kk[(size_t)(i0+g)*192 + h*16 + u2] = v;
      else         vv[(size_t)(i0+g)*192 + h*16 + (u2-16)] = v;
    }
  } else if (t < 336) {
    int m = t - 192;
    float b = bqp[m];
    #pragma unroll
    for (int g = 0; g < 8; g++) raw[g][m] = a1[g] + b;
  } else {
    int m2 = t - 336;
    float b = bkvp[m2];
    #pragma unroll
    for (int g = 0; g < 8; g++) raw[g][144 + m2] = a1[g] + b;
  }
  // scatter col2 = t+768 -> rawkv 48..431
  {
    int m2 = t + 48;
    float b = bkvp[m2];
    #pragma unroll
    for (int g = 0; g < 8; g++) raw[g][144 + m2] = a2[g] + b;
  }
  __syncthreads();

  // frame application: 8 i x (48 qp + 144 kvp) points
  for (int u = t; u < 8*192; u += 384) {
    int g = u / 192, pt = u % 192;
    const float* R = Rl[g];
    const float* T = Tl[g];
    if (pt < 48) {
      float p0 = raw[g][pt], p1 = raw[g][48+pt], p2 = raw[g][96+pt];
      float* d = qpts + ((size_t)(i0+g)*48 + pt)*3;
      d[0] = R[0]*p0 + R[1]*p1 + R[2]*p2 + T[0];
      d[1] = R[3]*p0 + R[4]*p1 + R[5]*p2 + T[1];
      d[2] = R[6]*p0 + R[7]*p1 + R[8]*p2 + T[2];
    } else {
      int m = pt - 48;
      float p0 = raw[g][144+m], p1 = raw[g][288+m], p2 = raw[g][432+m];
      float* d = kvpts + ((size_t)(i0+g)*144 + m)*3;
      d[0] = R[0]*p0 + R[1]*p1 + R[2]*p2 + T[0];
      d[1] = R[3]*p0 + R[4]*p1 + R[5]*p2 + T[1];
      d[2] = R[6]*p0 + R[7]*p1 + R[8]*p2 + T[2];
    }
  }
}

// ---------------------------------------------------------------------------
// K_PREP_ALL: Bq + afT (0..47), augT (48..239), Vq (240..671),
// Wout->bf16 (672..3839). grid 3840 x 256.
__global__ void k_prep_all(const float* __restrict__ kk, const float* __restrict__ kvpts,
                           const float* __restrict__ Wb, const float* __restrict__ q,
                           const float* __restrict__ qpts, const float* __restrict__ bb,
                           const float* __restrict__ head_w, const float* __restrict__ vv,
                           const float* __restrict__ Wout,
                           unsigned short* __restrict__ Bq, unsigned short* __restrict__ afT,
                           unsigned short* __restrict__ augT, unsigned short* __restrict__ Vq,
                           unsigned short* __restrict__ Wout_bf) {
  int b = blockIdx.x, t = threadIdx.x;
  if (b < 48) {
    int jt16 = b;
    for (int u = t; u < 768; u += 256) {
      int hp = u >> 6, kg = (u >> 4) & 3, l15 = u & 15;
      int j = jt16*16 + l15;
      unsigned short vals[8];
      #pragma unroll
      for (int e = 0; e < 8; e++) {
        int cc = kg*8 + e;
        float v;
        if (cc < 16) {
          v = kk[(size_t)j*192 + hp*16 + cc];
        } else if (cc < 28) {
          v = kvpts[(size_t)j*432 + hp*36 + (cc-16)];
        } else if (cc == 28) {
          float s2 = 0.f;
          #pragma unroll
          for (int m = 0; m < 12; m++) {
            float d = kvpts[(size_t)j*432 + hp*36 + m];
            s2 += d*d;
          }
          v = s2;
        } else if (cc == 29) {
          v = 1.0f;
        } else {
          v = 0.f;
        }
        vals[e] = f2bf(v);
      }
      *(us8*)(Bq + ((size_t)(jt16*12 + hp)*64 + kg*16 + l15)*8) = *(const us8*)vals;
    }
    if (b == 0) {
      int kg = t >> 6, l15 = (t >> 2) & 15, ks = t & 3;
      unsigned short vals[8];
      #pragma unroll
      for (int kc = 0; kc < 8; kc++) {
        vals[kc] = (l15 < 12)
          ? f2bf(0.5773502691896258f * Wb[(size_t)(ks*32 + kg*8 + kc)*12 + l15])
          : (unsigned short)0;
      }
      *(us8*)(afT + (size_t)t*8) = *(const us8*)vals;
    }
  } else if (b < 240) {
    int g = (b-48)*256 + t;   // < 49152
    int i = g >> 6, kg = (g >> 4) & 3, l15 = g & 15;
    const float sc1 = 0.14433756729740643f;   // sqrt(1/48)
    const float sc3 = 0.5773502691896258f;    // sqrt(1/3)
    float hw = (l15 < 12) ? log1pf(expf(head_w[l15])) * 0.13608276348795434f : 0.f;
    unsigned short vals[8];
    #pragma unroll
    for (int e = 0; e < 8; e++) {
      int idx = kg*8 + e;
      float v = 0.f;
      if (l15 < 12) {
        if (idx < 16) v = sc1 * q[(size_t)i*192 + l15*16 + idx];
        else if (idx < 28) v = hw * qpts[(size_t)i*144 + l15*12 + (idx-16)];
        else if (idx == 28) v = -0.5f * hw;
        else if (idx == 29) {
          float s2 = 0.f;
          #pragma unroll
          for (int m = 0; m < 12; m++) {
            float d = qpts[(size_t)i*144 + l15*12 + m];
            s2 += d*d;
          }
          v = sc3 * bb[l15] - 0.5f * hw * s2;
        }
      }
      vals[e] = f2bf(v);
    }
    *(us8*)(augT + (size_t)g*8) = *(const us8*)vals;
  } else if (b < 672) {
    int g = (b-240)*256 + t;   // < 110592
    int l15 = g & 15;
    int kg  = (g >> 4) & 3;
    int r2  = g >> 6;          // ((h*3+nt)*24 + ks)
    int ks  = r2 % 24;
    int hn  = r2 / 24;
    int nt  = hn % 3;
    int h   = hn / 3;
    int col = nt*16 + l15;
    unsigned short vals[8];
    #pragma unroll
    for (int e = 0; e < 8; e++) {
      int j = ks*32 + kg*8 + e;
      float v = 0.f;
      if (col < 16)      v = vv[(size_t)j*192 + h*16 + col];
      else if (col < 40) v = kvpts[(size_t)j*432 + h*36 + 12 + (col-16)];
      vals[e] = f2bf(v);
    }
    *(us8*)(Vq + (size_t)g*8) = *(const us8*)vals;
  } else {
    int g = (b-672)*256 + t;   // < 811008
    if (g < 811008) Wout_bf[g] = nf2bf(Wout[g]);
  }
}

// ---------------------------------------------------------------------------
// K_ZPASS v2 (unchanged from R12): 128-j chunks, 512 threads / 8 waves.
// grid (6 jt, 768 i) x 512.
#define PL2 136   // p_lds row stride in ushorts
__global__ void __launch_bounds__(512) k_zpass(
    const float* __restrict__ z, const unsigned short* __restrict__ Bq,
    const unsigned short* __restrict__ afT, const unsigned short* __restrict__ augT,
    unsigned short* __restrict__ p_bf, float* __restrict__ Pp,
    float* __restrict__ msbuf) {
  __shared__ unsigned short zt[128*128];    // 32 KB, z^T tile
  __shared__ unsigned short p_l[16*PL2];    // 4.25 KB
  __shared__ float redm[8][16];
  __shared__ float reds[8][16];
  int jt = blockIdx.x, i = blockIdx.y, t = threadIdx.x;
  int w = t >> 6, l = t & 63, kg = l >> 4, l15 = l & 15;
  const us8* afT8 = (const us8*)afT;
  const us8* augT8 = (const us8*)augT;
  const us8* Bq8 = (const us8*)Bq;
  us8 zero8 = {0,0,0,0,0,0,0,0};

  us8 af[4];
  #pragma unroll
  for (int ks = 0; ks < 4; ks++) af[ks] = afT8[(kg*16 + l15)*4 + ks];
  us8 aug = augT8[((size_t)i*4 + kg)*16 + l15];

  // ---- phase A: logits for this 128-j chunk; stage z^T into LDS
  int jloc = w*16 + l15;                 // 0..127
  int jcol = jt*128 + jloc;
  const float* zr = z + ((size_t)i*NN + jcol)*CZ;
  f32x4 accz = {0.f,0.f,0.f,0.f};
  f32x4 aa0 = {0.f,0.f,0.f,0.f}, aa1 = {0.f,0.f,0.f,0.f}, aa2 = {0.f,0.f,0.f,0.f};
  #pragma unroll
  for (int ks = 0; ks < 4; ks++) {
    float4 z0 = *(const float4*)(zr + ks*32 + kg*8);
    float4 z1 = *(const float4*)(zr + ks*32 + kg*8 + 4);
    bf16x8 bv;
    bv[0] = (__bf16)z0.x; bv[1] = (__bf16)z0.y; bv[2] = (__bf16)z0.z; bv[3] = (__bf16)z0.w;
    bv[4] = (__bf16)z1.x; bv[5] = (__bf16)z1.y; bv[6] = (__bf16)z1.z; bv[7] = (__bf16)z1.w;
    us8 bu = __builtin_bit_cast(us8, bv);
    #pragma unroll
    for (int e = 0; e < 8; e++) {
      int c = ks*32 + kg*8 + e;
      int js = (jloc + 16*((c>>3)&3) + 8*(c&7)) & 127;
      zt[c*128 + js] = bu[e];
    }
    accz = __builtin_amdgcn_mfma_f32_16x16x32_bf16(
        __builtin_bit_cast(bf16x8, af[ks]), bv, accz, 0, 0, 0);
  }
  int jtile = jt*8 + w;
  #pragma unroll
  for (int hp = 0; hp < 12; hp++) {
    us8 bqv = Bq8[(size_t)(jtile*12 + hp)*64 + kg*16 + l15];
    us8 sel = (l15 == hp) ? aug : zero8;
    f32x4* dst = (hp < 4) ? &aa0 : (hp < 8) ? &aa1 : &aa2;
    *dst = __builtin_amdgcn_mfma_f32_16x16x32_bf16(
        __builtin_bit_cast(bf16x8, sel), __builtin_bit_cast(bf16x8, bqv), *dst, 0, 0, 0);
  }
  f32x4 lg = (accz + aa0) + (aa1 + aa2);

  // ---- chunk-local softmax over 128 j for h = kg*4+r
  float mr[4];
  #pragma unroll
  for (int r = 0; r < 4; r++) {
    float m = lg[r];
    #pragma unroll
    for (int off = 1; off < 16; off <<= 1) m = fmaxf(m, __shfl_xor(m, off));
    mr[r] = m;
  }
  if (l15 == 0) {
    #pragma unroll
    for (int r = 0; r < 4; r++) redm[w][kg*4+r] = mr[r];
  }
  __syncthreads();
  float er[4], mloc[4], sr[4];
  #pragma unroll
  for (int r = 0; r < 4; r++) {
    int h = kg*4 + r;
    float m = redm[0][h];
    #pragma unroll
    for (int ww = 1; ww < 8; ww++) m = fmaxf(m, redm[ww][h]);
    mloc[r] = m;
    float e = expf(lg[r] - m);
    er[r] = e;
    float s = e;
    #pragma unroll
    for (int off = 1; off < 16; off <<= 1) s += __shfl_xor(s, off);
    sr[r] = s;
  }
  if (l15 == 0) {
    #pragma unroll
    for (int r = 0; r < 4; r++) reds[w][kg*4+r] = sr[r];
  }
  // write unnormalized p to LDS (rows h; rows 12..15 zeroed by kg==3)
  #pragma unroll
  for (int r = 0; r < 4; r++) {
    int row = kg*4 + r;
    p_l[row*PL2 + jloc] = (kg < 3) ? nf2bf(er[r]) : (unsigned short)0;
  }
  __syncthreads();
  if (w == 0 && l15 == 0 && kg < 3) {
    #pragma unroll
    for (int r = 0; r < 4; r++) {
      int h = kg*4 + r;
      float s_loc = reds[0][h] + reds[1][h] + reds[2][h] + reds[3][h]
                  + reds[4][h] + reds[5][h] + reds[6][h] + reds[7][h];
      msbuf[((size_t)i*6 + jt)*24 + h]      = mloc[r];
      msbuf[((size_t)i*6 + jt)*24 + 12 + h] = s_loc;
    }
  }

  // unnormalized p dump (k_ov rescales via alpha)
  {
    const us8* pl8 = (const us8*)p_l;   // 17 us8 per row
    us8* pg8 = (us8*)(p_bf + (size_t)i*12*768);
    if (t < 192) {
      int h = t >> 4, c8 = t & 15;
      pg8[h*96 + jt*16 + c8] = pl8[h*17 + c8];
    }
  }

  // ---- phase B: o_pair partial = p_loc @ z_chunk; wave w owns c-tile w
  {
    const us8* pl8 = (const us8*)p_l;
    f32x4 acc = {0.f,0.f,0.f,0.f};
    int c = w*16 + l15;
    int off = 16*((c>>3)&3) + 8*(c&7);
    #pragma unroll
    for (int ks = 0; ks < 4; ks++) {
      us8 av = pl8[l15*17 + ks*4 + kg];
      us8 b = *(const us8*)(zt + c*128 + ((ks*32 + kg*8 + off) & 127));
      acc = __builtin_amdgcn_mfma_f32_16x16x32_bf16(
          __builtin_bit_cast(bf16x8, av), __builtin_bit_cast(bf16x8, b), acc, 0, 0, 0);
    }
    #pragma unroll
    for (int r = 0; r < 4; r++) {
      int h = kg*4 + r;
      if (h < 12)
        Pp[(((size_t)i*6 + jt)*12 + h)*128 + c] = acc[r];
    }
  }
}

// ---------------------------------------------------------------------------
// K_OV (merged with flash combine): per-head GEMM with alpha-scaled
// unnormalized-p A-frags, plus o_pair combine for this h-slice.
// grid (48 i-tiles, 12 h) x 256.
__global__ void k_ov(const unsigned short* __restrict__ p_bf,
                     const unsigned short* __restrict__ Vq,
                     const float* __restrict__ Pp, const float* __restrict__ msbuf,
                     const float* __restrict__ rot, const float* __restrict__ trans,
                     float* __restrict__ cat) {
  __shared__ float alpha[16][6];
  __shared__ float opt[16][28];
  __shared__ float Rl[16][9];
  __shared__ float Tl[16][3];
  int it = blockIdx.x, h = blockIdx.y, t = threadIdx.x;
  int i0 = it*16;
  int w = t >> 6, l = t & 63, kg = l >> 4, l15 = l & 15;
  if (t < 144) Rl[t/9][t%9] = rot[(size_t)(i0 + t/9)*9 + (t%9)];
  if (t >= 192 && t < 240) {
    int u = t - 192;
    Tl[u/3][u%3] = trans[(size_t)(i0 + u/3)*3 + (u%3)];
  }
  // alpha for this block's 16 i's, this h
  if (t >= 240 && t < 256) {
    int iloc = t - 240;
    float ml[6], sl[6];
    float m = -1e30f;
    #pragma unroll
    for (int jt = 0; jt < 6; jt++) {
      ml[jt] = msbuf[((size_t)(i0+iloc)*6 + jt)*24 + h];
      sl[jt] = msbuf[((size_t)(i0+iloc)*6 + jt)*24 + 12 + h];
      m = fmaxf(m, ml[jt]);
    }
    float s = 0.f;
    float al[6];
    #pragma unroll
    for (int jt = 0; jt < 6; jt++) {
      al[jt] = expf(ml[jt] - m);
      s += sl[jt] * al[jt];
    }
    float invs = 1.0f / s;
    #pragma unroll
    for (int jt = 0; jt < 6; jt++) alpha[iloc][jt] = al[jt] * invs;
  }
  __syncthreads();

  f32x4 acc = {0.f,0.f,0.f,0.f};
  if (w < 3) {
    const unsigned short* prow = p_bf + ((size_t)(i0 + l15)*12 + h)*768 + kg*8;
    const us8* vq = (const us8*)Vq + (size_t)(h*3 + w)*24*64 + kg*16 + l15;
    for (int ks = 0; ks < 24; ks++) {
      us8 av = *(const us8*)(prow + ks*32);
      float a = alpha[l15][ks >> 2];
      bf16x8 avs;
      #pragma unroll
      for (int e = 0; e < 8; e++) avs[e] = (__bf16)(bf2f(av[e]) * a);
      us8 bv = vq[(size_t)ks*64];
      acc = __builtin_amdgcn_mfma_f32_16x16x32_bf16(
          avs, __builtin_bit_cast(bf16x8, bv), acc, 0, 0, 0);
    }
  }
  if (w == 0) {
    #pragma unroll
    for (int r = 0; r < 4; r++)
      cat[(size_t)(i0 + kg*4 + r)*CATC + h*16 + l15] = acc[r];
  } else if (w == 1) {
    #pragma unroll
    for (int r = 0; r < 4; r++) opt[kg*4 + r][l15] = acc[r];
  } else if (w == 2) {
    if (l15 < 8) {
      #pragma unroll
      for (int r = 0; r < 4; r++) opt[kg*4 + r][16 + l15] = acc[r];
    }
  }
  // o_pair combine for this h-slice (all waves; wave 3 has no MFMA work)
  for (int u = t; u < 2048; u += 256) {
    int iloc = u >> 7, c = u & 127;
    float a2 = 0.f;
    #pragma unroll
    for (int jt = 0; jt < 6; jt++)
      a2 += Pp[(((size_t)(i0+iloc)*6 + jt)*12 + h)*128 + c] * alpha[iloc][jt];
    cat[(size_t)(i0+iloc)*CATC + 576 + h*128 + c] = a2;
  }
  __syncthreads();
  if (t < 128) {
    int ip = t >> 3, p = t & 7;
    float x0 = opt[ip][p*3+0] - Tl[ip][0];
    float x1 = opt[ip][p*3+1] - Tl[ip][1];
    float x2 = opt[ip][p*3+2] - Tl[ip][2];
    const float* R = Rl[ip];
    float ox = R[0]*x0 + R[3]*x1 + R[6]*x2;
    float oy = R[1]*x0 + R[4]*x1 + R[7]*x2;
    float oz = R[2]*x0 + R[5]*x1 + R[8]*x2;
    float nrm = sqrtf(ox*ox + oy*oy + oz*oz + 1e-8f);
    float* c = cat + (size_t)(i0 + ip)*CATC;
    int m = h*8 + p;
    c[192 + m] = ox; c[288 + m] = oy; c[384 + m] = oz; c[480 + m] = nrm;
  }
}

// ---------------------------------------------------------------------------
// K6: out = cat @ Wout + bout, Wout in bf16. grid 256 x 384, 3 rows/block.
#define OROWS 3
__global__ void k_out(const float* __restrict__ cat, const unsigned short* __restrict__ Wout_bf,
                      const float* __restrict__ bout, float* __restrict__ out) {
  __shared__ float cl[OROWS*CATC];
  int i0 = blockIdx.x*OROWS, t = threadIdx.x;
  for (int idx = t; idx < OROWS*CATC; idx += 384) cl[idx] = cat[(size_t)i0*CATC + idx];
  __syncthreads();
  float acc[OROWS];
  #pragma unroll
  for (int g = 0; g < OROWS; g++) acc[g] = 0.f;
  for (int r = 0; r < CATC; r += 8) {
    float wv[8];
    #pragma unroll
    for (int u = 0; u < 8; u++) wv[u] = bf2f(Wout_bf[(size_t)(r+u)*384 + t]);
    #pragma unroll
    for (int u = 0; u < 8; u++) {
      #pragma unroll
      for (int g = 0; g < OROWS; g++) acc[g] += cl[g*CATC + r + u] * wv[u];
    }
  }
  float bo = bout[t];
  #pragma unroll
  for (int g = 0; g < OROWS; g++) out[(size_t)(i0+g)*384 + t] = acc[g] + bo;
}

// ---------------------------------------------------------------------------
extern "C" void kernel_launch(void* const* d_in, const int* in_sizes, int n_in,
                              void* d_out, int out_size, void* d_ws, size_t ws_size,
                              hipStream_t stream) {
  const float* s      = (const float*)d_in[0];
  const float* z      = (const float*)d_in[1];
  const float* rot    = (const float*)d_in[2];
  const float* trans  = (const float*)d_in[3];
  const float* Wq     = (const float*)d_in[4];
  const float* bq     = (const float*)d_in[5];
  const float* Wkv    = (const float*)d_in[6];
  const float* bkv    = (const float*)d_in[7];
  const float* Wqp    = (const float*)d_in[8];
  const float* bqp    = (const float*)d_in[9];
  const float* Wkvp   = (const float*)d_in[10];
  const float* bkvp   = (const float*)d_in[11];
  const float* Wb     = (const float*)d_in[12];
  const float* bb     = (const float*)d_in[13];
  const float* head_w = (const float*)d_in[14];
  const float* Wout   = (const float*)d_in[15];
  const float* bout   = (const float*)d_in[16];
  float* out = (float*)d_out;

  float* ws    = (float*)d_ws;
  float* q     = ws;                    // 147456
  float* kk    = q     + 147456;        // 147456
  float* vv    = kk    + 147456;        // 147456
  float* qpts  = vv    + 147456;        // 110592
  float* kvpts = qpts  + 110592;        // 331776
  unsigned short* p_bf = (unsigned short*)(kvpts + 331776);  // 7077888 ushorts
  float* cat   = (float*)(p_bf + 7077888);                   // 1622016
  unsigned short* Bq  = (unsigned short*)(cat + 1622016);    // 294912 ushorts
  unsigned short* Vq  = Bq + 294912;                         // 884736 ushorts
  unsigned short* afT = Vq + 884736;                         // 2048 ushorts
  unsigned short* augT= afT + 2048;                          // 393216 ushorts
  float* Pp    = (float*)(augT + 393216);                    // 7077888 floats
  float* msbuf = Pp + 7077888;                               // 110592 floats
  unsigned short* Wout_bf = (unsigned short*)(msbuf + 110592); // 811008 ushorts

  k_projg<<<96, 384, 0, stream>>>(s, Wq, Wkv, Wqp, Wkvp, rot, trans,
                                  bq, bkv, bqp, bkvp, q, kk, vv, qpts, kvpts);
  k_prep_all<<<3840, 256, 0, stream>>>(kk, kvpts, Wb, q, qpts, bb, head_w, vv,
                                       Wout, Bq, afT, augT, Vq, Wout_bf);
  k_zpass<<<dim3(6, 768), 512, 0, stream>>>(z, Bq, afT, augT, p_bf, Pp, msbuf);
  k_ov<<<dim3(48, 12), 256, 0, stream>>>(p_bf, Vq, Pp, msbuf, rot, trans, cat);
  k_out<<<256, 384, 0, stream>>>(cat, Wout_bf, bout, out);
}

// Round 14
// 301.778 us; speedup vs baseline: 1.0107x; 1.0107x over previous
//
#include <hip/hip_runtime.h>
#include <hip/hip_bf16.h>
#include <cmath>

// Problem constants
#define NN 768
#define CS 384
#define CZ 128
#define CH 16
#define HH 12
#define PQ 4
#define PV 8
#define CATC 2112           // H*(CZ+CH+PV*4)

typedef __attribute__((ext_vector_type(8))) __bf16 bf16x8;
typedef __attribute__((ext_vector_type(8))) unsigned short us8;
typedef __attribute__((ext_vector_type(4))) float f32x4;

__device__ __forceinline__ unsigned short f2bf(float f) {
  unsigned int u = __builtin_bit_cast(unsigned int, f);
  u += 0x7FFFu + ((u >> 16) & 1u);   // RNE
  return (unsigned short)(u >> 16);
}
__device__ __forceinline__ float bf2f(unsigned short u) {
  return __builtin_bit_cast(float, ((unsigned int)u) << 16);
}
__device__ __forceinline__ unsigned short nf2bf(float f) {
  __bf16 b = (__bf16)f;
  return __builtin_bit_cast(unsigned short, b);
}

// ---------------------------------------------------------------------------
// K_PROJG: projection GEMM, 8 i-rows/block, fp32, grid 96 x 384.
// Thread owns 3 virtual columns {t, t+384, t+768} of [Wq|Wkv|Wqp|Wkvp],
// read DIRECTLY from the four matrices (per-wave contiguous lanes -> coalesced).
__global__ void __launch_bounds__(384) k_projg(
    const float* __restrict__ s,
    const float* __restrict__ Wq, const float* __restrict__ Wkv,
    const float* __restrict__ Wqp, const float* __restrict__ Wkvp,
    const float* __restrict__ rot, const float* __restrict__ trans,
    const float* __restrict__ bq, const float* __restrict__ bkv,
    const float* __restrict__ bqp, const float* __restrict__ bkvp,
    float* __restrict__ q, float* __restrict__ kk, float* __restrict__ vv,
    float* __restrict__ qpts, float* __restrict__ kvpts) {
  __shared__ float sl[8][384];
  __shared__ float raw[8][576];    // [rawq(144)|rawkv(432)] per i, bias included
  __shared__ float Rl[8][9];
  __shared__ float Tl[8][3];
  int i0 = blockIdx.x*8, t = threadIdx.x;
  #pragma unroll
  for (int k = 0; k < 8; k++) sl[k][t] = s[(size_t)(i0+k)*CS + t];
  if (t < 72) Rl[t/9][t%9] = rot[(size_t)i0*9 + t];
  else if (t < 96) { int u = t-72; Tl[u/3][u%3] = trans[(size_t)i0*3 + u]; }
  __syncthreads();

  // column -> (matrix base, stride, col) mapping
  const float* w0; int s0_, c0_;
  const float* w1; int s1_, c1_;
  const float* w2; int s2_, c2_;
  if (t < 192) { w0 = Wq;   s0_ = 192; c0_ = t; }
  else         { w0 = Wkv;  s0_ = 384; c0_ = t - 192; }
  if (t < 192)      { w1 = Wkv;  s1_ = 384; c1_ = t + 192; }
  else if (t < 336) { w1 = Wqp;  s1_ = 144; c1_ = t - 192; }
  else              { w1 = Wkvp; s1_ = 432; c1_ = t - 336; }
  w2 = Wkvp; s2_ = 432; c2_ = t + 48;

  float a0[8], a1[8], a2[8];
  #pragma unroll
  for (int g = 0; g < 8; g++) { a0[g]=0.f; a1[g]=0.f; a2[g]=0.f; }
  #pragma unroll 4
  for (int c4 = 0; c4 < 96; c4++) {
    float4 sv[8];
    #pragma unroll
    for (int g = 0; g < 8; g++) sv[g] = *(const float4*)&sl[g][c4*4];
    #pragma unroll
    for (int e = 0; e < 4; e++) {
      int c = c4*4 + e;
      float wv0 = w0[(size_t)c*s0_ + c0_];
      float wv1 = w1[(size_t)c*s1_ + c1_];
      float wv2 = w2[(size_t)c*s2_ + c2_];
      #pragma unroll
      for (int g = 0; g < 8; g++) {
        float svv = (e==0)?sv[g].x:(e==1)?sv[g].y:(e==2)?sv[g].z:sv[g].w;
        a0[g] += svv*wv0; a1[g] += svv*wv1; a2[g] += svv*wv2;
      }
    }
  }
  // scatter col0 = t
  if (t < 192) {
    float b = bq[t];
    #pragma unroll
    for (int g = 0; g < 8; g++) q[(size_t)(i0+g)*192 + t] = a0[g] + b;
  } else {
    int cc = t - 192;
    float b = bkv[cc];
    int h = cc >> 5, u2 = cc & 31;
    #pragma unroll
    for (int g = 0; g < 8; g++) {
      float v = a0[g] + b;
      if (u2 < 16) kk[(size_t)(i0+g)*192 + h*16 + u2] = v;
      else         vv[(size_t)(i0+g)*192 + h*16 + (u2-16)] = v;
    }
  }
  // scatter col1 = t+384
  if (t < 192) {
    int cc = t + 192;
    float b = bkv[cc];
    int h = cc >> 5, u2 = cc & 31;
    #pragma unroll
    for (int g = 0; g < 8; g++) {
      float v = a1[g] + b;
      if (u2 < 16) kk[(size_t)(i0+g)*192 + h*16 + u2] = v;
      else         vv[(size_t)(i0+g)*192 + h*16 + (u2-16)] = v;
    }
  } else if (t < 336) {
    int m = t - 192;
    float b = bqp[m];
    #pragma unroll
    for (int g = 0; g < 8; g++) raw[g][m] = a1[g] + b;
  } else {
    int m2 = t - 336;
    float b = bkvp[m2];
    #pragma unroll
    for (int g = 0; g < 8; g++) raw[g][144 + m2] = a1[g] + b;
  }
  // scatter col2 = t+768 -> rawkv 48..431
  {
    int m2 = t + 48;
    float b = bkvp[m2];
    #pragma unroll
    for (int g = 0; g < 8; g++) raw[g][144 + m2] = a2[g] + b;
  }
  __syncthreads();

  // frame application: 8 i x (48 qp + 144 kvp) points
  for (int u = t; u < 8*192; u += 384) {
    int g = u / 192, pt = u % 192;
    const float* R = Rl[g];
    const float* T = Tl[g];
    if (pt < 48) {
      float p0 = raw[g][pt], p1 = raw[g][48+pt], p2 = raw[g][96+pt];
      float* d = qpts + ((size_t)(i0+g)*48 + pt)*3;
      d[0] = R[0]*p0 + R[1]*p1 + R[2]*p2 + T[0];
      d[1] = R[3]*p0 + R[4]*p1 + R[5]*p2 + T[1];
      d[2] = R[6]*p0 + R[7]*p1 + R[8]*p2 + T[2];
    } else {
      int m = pt - 48;
      float p0 = raw[g][144+m], p1 = raw[g][288+m], p2 = raw[g][432+m];
      float* d = kvpts + ((size_t)(i0+g)*144 + m)*3;
      d[0] = R[0]*p0 + R[1]*p1 + R[2]*p2 + T[0];
      d[1] = R[3]*p0 + R[4]*p1 + R[5]*p2 + T[1];
      d[2] = R[6]*p0 + R[7]*p1 + R[8]*p2 + T[2];
    }
  }
}

// ---------------------------------------------------------------------------
// K_PREP_ALL: Bq + afT (0..47), augT (48..239), Vq (240..671),
// Wout->bf16 (672..3839). grid 3840 x 256.
__global__ void k_prep_all(const float* __restrict__ kk, const float* __restrict__ kvpts,
                           const float* __restrict__ Wb, const float* __restrict__ q,
                           const float* __restrict__ qpts, const float* __restrict__ bb,
                           const float* __restrict__ head_w, const float* __restrict__ vv,
                           const float* __restrict__ Wout,
                           unsigned short* __restrict__ Bq, unsigned short* __restrict__ afT,
                           unsigned short* __restrict__ augT, unsigned short* __restrict__ Vq,
                           unsigned short* __restrict__ Wout_bf) {
  int b = blockIdx.x, t = threadIdx.x;
  if (b < 48) {
    int jt16 = b;
    for (int u = t; u < 768; u += 256) {
      int hp = u >> 6, kg = (u >> 4) & 3, l15 = u & 15;
      int j = jt16*16 + l15;
      unsigned short vals[8];
      #pragma unroll
      for (int e = 0; e < 8; e++) {
        int cc = kg*8 + e;
        float v;
        if (cc < 16) {
          v = kk[(size_t)j*192 + hp*16 + cc];
        } else if (cc < 28) {
          v = kvpts[(size_t)j*432 + hp*36 + (cc-16)];
        } else if (cc == 28) {
          float s2 = 0.f;
          #pragma unroll
          for (int m = 0; m < 12; m++) {
            float d = kvpts[(size_t)j*432 + hp*36 + m];
            s2 += d*d;
          }
          v = s2;
        } else if (cc == 29) {
          v = 1.0f;
        } else {
          v = 0.f;
        }
        vals[e] = f2bf(v);
      }
      *(us8*)(Bq + ((size_t)(jt16*12 + hp)*64 + kg*16 + l15)*8) = *(const us8*)vals;
    }
    if (b == 0) {
      int kg = t >> 6, l15 = (t >> 2) & 15, ks = t & 3;
      unsigned short vals[8];
      #pragma unroll
      for (int kc = 0; kc < 8; kc++) {
        vals[kc] = (l15 < 12)
          ? f2bf(0.5773502691896258f * Wb[(size_t)(ks*32 + kg*8 + kc)*12 + l15])
          : (unsigned short)0;
      }
      *(us8*)(afT + (size_t)t*8) = *(const us8*)vals;
    }
  } else if (b < 240) {
    int g = (b-48)*256 + t;   // < 49152
    int i = g >> 6, kg = (g >> 4) & 3, l15 = g & 15;
    const float sc1 = 0.14433756729740643f;   // sqrt(1/48)
    const float sc3 = 0.5773502691896258f;    // sqrt(1/3)
    float hw = (l15 < 12) ? log1pf(expf(head_w[l15])) * 0.13608276348795434f : 0.f;
    unsigned short vals[8];
    #pragma unroll
    for (int e = 0; e < 8; e++) {
      int idx = kg*8 + e;
      float v = 0.f;
      if (l15 < 12) {
        if (idx < 16) v = sc1 * q[(size_t)i*192 + l15*16 + idx];
        else if (idx < 28) v = hw * qpts[(size_t)i*144 + l15*12 + (idx-16)];
        else if (idx == 28) v = -0.5f * hw;
        else if (idx == 29) {
          float s2 = 0.f;
          #pragma unroll
          for (int m = 0; m < 12; m++) {
            float d = qpts[(size_t)i*144 + l15*12 + m];
            s2 += d*d;
          }
          v = sc3 * bb[l15] - 0.5f * hw * s2;
        }
      }
      vals[e] = f2bf(v);
    }
    *(us8*)(augT + (size_t)g*8) = *(const us8*)vals;
  } else if (b < 672) {
    int g = (b-240)*256 + t;   // < 110592
    int l15 = g & 15;
    int kg  = (g >> 4) & 3;
    int r2  = g >> 6;          // ((h*3+nt)*24 + ks)
    int ks  = r2 % 24;
    int hn  = r2 / 24;
    int nt  = hn % 3;
    int h   = hn / 3;
    int col = nt*16 + l15;
    unsigned short vals[8];
    #pragma unroll
    for (int e = 0; e < 8; e++) {
      int j = ks*32 + kg*8 + e;
      float v = 0.f;
      if (col < 16)      v = vv[(size_t)j*192 + h*16 + col];
      else if (col < 40) v = kvpts[(size_t)j*432 + h*36 + 12 + (col-16)];
      vals[e] = f2bf(v);
    }
    *(us8*)(Vq + (size_t)g*8) = *(const us8*)vals;
  } else {
    int g = (b-672)*256 + t;   // < 811008
    if (g < 811008) Wout_bf[g] = nf2bf(Wout[g]);
  }
}

// ---------------------------------------------------------------------------
// K_ZPASS v2 (unchanged): 128-j chunks, 512 threads / 8 waves.
// grid (6 jt, 768 i) x 512.
#define PL2 136   // p_lds row stride in ushorts
__global__ void __launch_bounds__(512) k_zpass(
    const float* __restrict__ z, const unsigned short* __restrict__ Bq,
    const unsigned short* __restrict__ afT, const unsigned short* __restrict__ augT,
    unsigned short* __restrict__ p_bf, float* __restrict__ Pp,
    float* __restrict__ msbuf) {
  __shared__ unsigned short zt[128*128];    // 32 KB, z^T tile
  __shared__ unsigned short p_l[16*PL2];    // 4.25 KB
  __shared__ float redm[8][16];
  __shared__ float reds[8][16];
  int jt = blockIdx.x, i = blockIdx.y, t = threadIdx.x;
  int w = t >> 6, l = t & 63, kg = l >> 4, l15 = l & 15;
  const us8* afT8 = (const us8*)afT;
  const us8* augT8 = (const us8*)augT;
  const us8* Bq8 = (const us8*)Bq;
  us8 zero8 = {0,0,0,0,0,0,0,0};

  us8 af[4];
  #pragma unroll
  for (int ks = 0; ks < 4; ks++) af[ks] = afT8[(kg*16 + l15)*4 + ks];
  us8 aug = augT8[((size_t)i*4 + kg)*16 + l15];

  // ---- phase A: logits for this 128-j chunk; stage z^T into LDS
  int jloc = w*16 + l15;                 // 0..127
  int jcol = jt*128 + jloc;
  const float* zr = z + ((size_t)i*NN + jcol)*CZ;
  f32x4 accz = {0.f,0.f,0.f,0.f};
  f32x4 aa0 = {0.f,0.f,0.f,0.f}, aa1 = {0.f,0.f,0.f,0.f}, aa2 = {0.f,0.f,0.f,0.f};
  #pragma unroll
  for (int ks = 0; ks < 4; ks++) {
    float4 z0 = *(const float4*)(zr + ks*32 + kg*8);
    float4 z1 = *(const float4*)(zr + ks*32 + kg*8 + 4);
    bf16x8 bv;
    bv[0] = (__bf16)z0.x; bv[1] = (__bf16)z0.y; bv[2] = (__bf16)z0.z; bv[3] = (__bf16)z0.w;
    bv[4] = (__bf16)z1.x; bv[5] = (__bf16)z1.y; bv[6] = (__bf16)z1.z; bv[7] = (__bf16)z1.w;
    us8 bu = __builtin_bit_cast(us8, bv);
    #pragma unroll
    for (int e = 0; e < 8; e++) {
      int c = ks*32 + kg*8 + e;
      int js = (jloc + 16*((c>>3)&3) + 8*(c&7)) & 127;
      zt[c*128 + js] = bu[e];
    }
    accz = __builtin_amdgcn_mfma_f32_16x16x32_bf16(
        __builtin_bit_cast(bf16x8, af[ks]), bv, accz, 0, 0, 0);
  }
  int jtile = jt*8 + w;
  #pragma unroll
  for (int hp = 0; hp < 12; hp++) {
    us8 bqv = Bq8[(size_t)(jtile*12 + hp)*64 + kg*16 + l15];
    us8 sel = (l15 == hp) ? aug : zero8;
    f32x4* dst = (hp < 4) ? &aa0 : (hp < 8) ? &aa1 : &aa2;
    *dst = __builtin_amdgcn_mfma_f32_16x16x32_bf16(
        __builtin_bit_cast(bf16x8, sel), __builtin_bit_cast(bf16x8, bqv), *dst, 0, 0, 0);
  }
  f32x4 lg = (accz + aa0) + (aa1 + aa2);

  // ---- chunk-local softmax over 128 j for h = kg*4+r
  float mr[4];
  #pragma unroll
  for (int r = 0; r < 4; r++) {
    float m = lg[r];
    #pragma unroll
    for (int off = 1; off < 16; off <<= 1) m = fmaxf(m, __shfl_xor(m, off));
    mr[r] = m;
  }
  if (l15 == 0) {
    #pragma unroll
    for (int r = 0; r < 4; r++) redm[w][kg*4+r] = mr[r];
  }
  __syncthreads();
  float er[4], mloc[4], sr[4];
  #pragma unroll
  for (int r = 0; r < 4; r++) {
    int h = kg*4 + r;
    float m = redm[0][h];
    #pragma unroll
    for (int ww = 1; ww < 8; ww++) m = fmaxf(m, redm[ww][h]);
    mloc[r] = m;
    float e = expf(lg[r] - m);
    er[r] = e;
    float s = e;
    #pragma unroll
    for (int off = 1; off < 16; off <<= 1) s += __shfl_xor(s, off);
    sr[r] = s;
  }
  if (l15 == 0) {
    #pragma unroll
    for (int r = 0; r < 4; r++) reds[w][kg*4+r] = sr[r];
  }
  // write unnormalized p to LDS (rows h; rows 12..15 zeroed by kg==3)
  #pragma unroll
  for (int r = 0; r < 4; r++) {
    int row = kg*4 + r;
    p_l[row*PL2 + jloc] = (kg < 3) ? nf2bf(er[r]) : (unsigned short)0;
  }
  __syncthreads();
  if (w == 0 && l15 == 0 && kg < 3) {
    #pragma unroll
    for (int r = 0; r < 4; r++) {
      int h = kg*4 + r;
      float s_loc = reds[0][h] + reds[1][h] + reds[2][h] + reds[3][h]
                  + reds[4][h] + reds[5][h] + reds[6][h] + reds[7][h];
      msbuf[((size_t)i*6 + jt)*24 + h]      = mloc[r];
      msbuf[((size_t)i*6 + jt)*24 + 12 + h] = s_loc;
    }
  }

  // unnormalized p dump (k_comb rescales in place)
  {
    const us8* pl8 = (const us8*)p_l;   // 17 us8 per row
    us8* pg8 = (us8*)(p_bf + (size_t)i*12*768);
    if (t < 192) {
      int h = t >> 4, c8 = t & 15;
      pg8[h*96 + jt*16 + c8] = pl8[h*17 + c8];
    }
  }

  // ---- phase B: o_pair partial = p_loc @ z_chunk; wave w owns c-tile w
  {
    const us8* pl8 = (const us8*)p_l;
    f32x4 acc = {0.f,0.f,0.f,0.f};
    int c = w*16 + l15;
    int off = 16*((c>>3)&3) + 8*(c&7);
    #pragma unroll
    for (int ks = 0; ks < 4; ks++) {
      us8 av = pl8[l15*17 + ks*4 + kg];
      us8 b = *(const us8*)(zt + c*128 + ((ks*32 + kg*8 + off) & 127));
      acc = __builtin_amdgcn_mfma_f32_16x16x32_bf16(
          __builtin_bit_cast(bf16x8, av), __builtin_bit_cast(bf16x8, b), acc, 0, 0, 0);
    }
    #pragma unroll
    for (int r = 0; r < 4; r++) {
      int h = kg*4 + r;
      if (h < 12)
        Pp[(((size_t)i*6 + jt)*12 + h)*128 + c] = acc[r];
    }
  }
}

// ---------------------------------------------------------------------------
// K_COMB: flash combine over 6 chunks; normalize p_bf in place. grid 768 x 256.
__global__ void k_comb(const float* __restrict__ Pp, const float* __restrict__ msbuf,
                       unsigned short* __restrict__ p_bf, float* __restrict__ cat) {
  __shared__ float alpha[12][6];   // [h][jt]
  int i = blockIdx.x, t = threadIdx.x;
  if (t < 12) {
    int h = t;
    float ml[6];
    float m = -1e30f;
    #pragma unroll
    for (int jt = 0; jt < 6; jt++) {
      ml[jt] = msbuf[((size_t)i*6 + jt)*24 + h];
      m = fmaxf(m, ml[jt]);
    }
    float s = 0.f;
    float al[6];
    #pragma unroll
    for (int jt = 0; jt < 6; jt++) {
      al[jt] = expf(ml[jt] - m);
      s += msbuf[((size_t)i*6 + jt)*24 + 12 + h] * al[jt];
    }
    float invs = 1.0f / s;
    #pragma unroll
    for (int jt = 0; jt < 6; jt++) alpha[h][jt] = al[jt] * invs;
  }
  __syncthreads();
  // o_pair
  for (int u = t; u < 1536; u += 256) {
    int h = u >> 7, c = u & 127;
    float acc = 0.f;
    #pragma unroll
    for (int jt = 0; jt < 6; jt++)
      acc += Pp[(((size_t)i*6 + jt)*12 + h)*128 + c] * alpha[h][jt];
    cat[(size_t)i*CATC + 576 + h*128 + c] = acc;
  }
  // normalize p for k_ov
  us8* pg8 = (us8*)(p_bf + (size_t)i*12*768);
  for (int u = t; u < 1152; u += 256) {
    int h = u / 96, c8 = u % 96, jt = c8 >> 4;
    float a = alpha[h][jt];
    us8 v = pg8[h*96 + c8];
    #pragma unroll
    for (int e = 0; e < 8; e++) v[e] = nf2bf(bf2f(v[e]) * a);
    pg8[h*96 + c8] = v;
  }
}

// ---------------------------------------------------------------------------
// K4 (MFMA): per-head GEMM P_h[768x768] @ V_h[768x40] -> o and o_pt(+norm).
// grid (48 i-tiles, 12 h) x 256.
__global__ void k_ov(const unsigned short* __restrict__ p_bf,
                     const unsigned short* __restrict__ Vq,
                     const float* __restrict__ rot, const float* __restrict__ trans,
                     float* __restrict__ cat) {
  __shared__ float opt[16][28];
  __shared__ float Rl[16][9];
  __shared__ float Tl[16][3];
  int it = blockIdx.x, h = blockIdx.y, t = threadIdx.x;
  int i0 = it*16;
  int w = t >> 6, l = t & 63, kg = l >> 4, l15 = l & 15;
  if (t < 144) Rl[t/9][t%9] = rot[(size_t)(i0 + t/9)*9 + (t%9)];
  if (t >= 192 && t < 240) {
    int u = t - 192;
    Tl[u/3][u%3] = trans[(size_t)(i0 + u/3)*3 + (u%3)];
  }
  f32x4 acc = {0.f,0.f,0.f,0.f};
  if (w < 3) {
    const unsigned short* prow = p_bf + ((size_t)(i0 + l15)*12 + h)*768 + kg*8;
    const us8* vq = (const us8*)Vq + (size_t)(h*3 + w)*24*64 + kg*16 + l15;
    for (int ks = 0; ks < 24; ks++) {
      us8 av = *(const us8*)(prow + ks*32);
      us8 bv = vq[(size_t)ks*64];
      acc = __builtin_amdgcn_mfma_f32_16x16x32_bf16(
          __builtin_bit_cast(bf16x8, av), __builtin_bit_cast(bf16x8, bv), acc, 0, 0, 0);
    }
  }
  if (w == 0) {
    #pragma unroll
    for (int r = 0; r < 4; r++)
      cat[(size_t)(i0 + kg*4 + r)*CATC + h*16 + l15] = acc[r];
  } else if (w == 1) {
    #pragma unroll
    for (int r = 0; r < 4; r++) opt[kg*4 + r][l15] = acc[r];
  } else if (w == 2) {
    if (l15 < 8) {
      #pragma unroll
      for (int r = 0; r < 4; r++) opt[kg*4 + r][16 + l15] = acc[r];
    }
  }
  __syncthreads();
  if (t < 128) {
    int ip = t >> 3, p = t & 7;
    float x0 = opt[ip][p*3+0] - Tl[ip][0];
    float x1 = opt[ip][p*3+1] - Tl[ip][1];
    float x2 = opt[ip][p*3+2] - Tl[ip][2];
    const float* R = Rl[ip];
    float ox = R[0]*x0 + R[3]*x1 + R[6]*x2;
    float oy = R[1]*x0 + R[4]*x1 + R[7]*x2;
    float oz = R[2]*x0 + R[5]*x1 + R[8]*x2;
    float nrm = sqrtf(ox*ox + oy*oy + oz*oz + 1e-8f);
    float* c = cat + (size_t)(i0 + ip)*CATC;
    int m = h*8 + p;
    c[192 + m] = ox; c[288 + m] = oy; c[384 + m] = oz; c[480 + m] = nrm;
  }
}

// ---------------------------------------------------------------------------
// K6: out = cat @ Wout + bout, Wout in bf16. grid 256 x 384, 3 rows/block.
#define OROWS 3
__global__ void k_out(const float* __restrict__ cat, const unsigned short* __restrict__ Wout_bf,
                      const float* __restrict__ bout, float* __restrict__ out) {
  __shared__ float cl[OROWS*CATC];
  int i0 = blockIdx.x*OROWS, t = threadIdx.x;
  for (int idx = t; idx < OROWS*CATC; idx += 384) cl[idx] = cat[(size_t)i0*CATC + idx];
  __syncthreads();
  float acc[OROWS];
  #pragma unroll
  for (int g = 0; g < OROWS; g++) acc[g] = 0.f;
  for (int r = 0; r < CATC; r += 8) {
    float wv[8];
    #pragma unroll
    for (int u = 0; u < 8; u++) wv[u] = bf2f(Wout_bf[(size_t)(r+u)*384 + t]);
    #pragma unroll
    for (int u = 0; u < 8; u++) {
      #pragma unroll
      for (int g = 0; g < OROWS; g++) acc[g] += cl[g*CATC + r + u] * wv[u];
    }
  }
  float bo = bout[t];
  #pragma unroll
  for (int g = 0; g < OROWS; g++) out[(size_t)(i0+g)*384 + t] = acc[g] + bo;
}

// ---------------------------------------------------------------------------
extern "C" void kernel_launch(void* const* d_in, const int* in_sizes, int n_in,
                              void* d_out, int out_size, void* d_ws, size_t ws_size,
                              hipStream_t stream) {
  const float* s      = (const float*)d_in[0];
  const float* z      = (const float*)d_in[1];
  const float* rot    = (const float*)d_in[2];
  const float* trans  = (const float*)d_in[3];
  const float* Wq     = (const float*)d_in[4];
  const float* bq     = (const float*)d_in[5];
  const float* Wkv    = (const float*)d_in[6];
  const float* bkv    = (const float*)d_in[7];
  const float* Wqp    = (const float*)d_in[8];
  const float* bqp    = (const float*)d_in[9];
  const float* Wkvp   = (const float*)d_in[10];
  const float* bkvp   = (const float*)d_in[11];
  const float* Wb     = (const float*)d_in[12];
  const float* bb     = (const float*)d_in[13];
  const float* head_w = (const float*)d_in[14];
  const float* Wout   = (const float*)d_in[15];
  const float* bout   = (const float*)d_in[16];
  float* out = (float*)d_out;

  float* ws    = (float*)d_ws;
  float* q     = ws;                    // 147456
  float* kk    = q     + 147456;        // 147456
  float* vv    = kk    + 147456;        // 147456
  float* qpts  = vv    + 147456;        // 110592
  float* kvpts = qpts  + 110592;        // 331776
  unsigned short* p_bf = (unsigned short*)(kvpts + 331776);  // 7077888 ushorts
  float* cat   = (float*)(p_bf + 7077888);                   // 1622016
  unsigned short* Bq  = (unsigned short*)(cat + 1622016);    // 294912 ushorts
  unsigned short* Vq  = Bq + 294912;                         // 884736 ushorts
  unsigned short* afT = Vq + 884736;                         // 2048 ushorts
  unsigned short* augT= afT + 2048;                          // 393216 ushorts
  float* Pp    = (float*)(augT + 393216);                    // 7077888 floats
  float* msbuf = Pp + 7077888;                               // 110592 floats
  unsigned short* Wout_bf = (unsigned short*)(msbuf + 110592); // 811008 ushorts

  k_projg<<<96, 384, 0, stream>>>(s, Wq, Wkv, Wqp, Wkvp, rot, trans,
                                  bq, bkv, bqp, bkvp, q, kk, vv, qpts, kvpts);
  k_prep_all<<<3840, 256, 0, stream>>>(kk, kvpts, Wb, q, qpts, bb, head_w, vv,
                                       Wout, Bq, afT, augT, Vq, Wout_bf);
  k_zpass<<<dim3(6, 768), 512, 0, stream>>>(z, Bq, afT, augT, p_bf, Pp, msbuf);
  k_comb<<<768, 256, 0, stream>>>(Pp, msbuf, p_bf, cat);
  k_ov<<<dim3(48, 12), 256, 0, stream>>>(p_bf, Vq, rot, trans, cat);
  k_out<<<256, 384, 0, stream>>>(cat, Wout_bf, bout, out);
}